// Round 1
// baseline (543.951 us; speedup 1.0000x reference)
//
#include <hip/hip_runtime.h>
#include <math.h>

#define Himg 128
#define Wimg 128
#define HW   16384      // 128*128
#define Cin  64
#define Kk   9
#define OUTC 128
#define Bsz  8

// ---------------------------------------------------------------------------
// Kernel 0: repack w_conv[o][c][k] -> wpk[k][c][o]  (coalesced tile loads later)
// ---------------------------------------------------------------------------
__global__ __launch_bounds__(256) void repack_w(const float* __restrict__ w_conv,
                                                float* __restrict__ wpk) {
    int idx = blockIdx.x * 256 + threadIdx.x;            // 0 .. 73727
    if (idx >= Kk * Cin * OUTC) return;
    int o = idx % OUTC;
    int c = (idx / OUTC) % Cin;
    int k = idx / (OUTC * Cin);
    wpk[idx] = w_conv[(o * Cin + c) * 9 + k];
}

// ---------------------------------------------------------------------------
// Kernel 1: offset conv (18 ch) + mask conv (9 ch) + sigmoid, direct form.
// One thread per pixel, 27 fp32 accumulators. Weights are wave-uniform ->
// scalar loads; x loads are coalesced along w.
// ---------------------------------------------------------------------------
__global__ __launch_bounds__(256) void offs_mask(
        const float* __restrict__ x,
        const float* __restrict__ w_offset, const float* __restrict__ b_offset,
        const float* __restrict__ w_mask,   const float* __restrict__ b_mask,
        float* __restrict__ dy_out, float* __restrict__ dx_out,
        float* __restrict__ mk_out) {
    int g   = blockIdx.x * 256 + threadIdx.x;            // 0 .. B*HW-1
    int b   = g >> 14;
    int rem = g & (HW - 1);
    int h   = rem >> 7;
    int w   = rem & (Wimg - 1);

    float acc[27];
#pragma unroll
    for (int j = 0; j < 18; ++j) acc[j] = b_offset[j];
#pragma unroll
    for (int j = 0; j < 9; ++j)  acc[18 + j] = b_mask[j];

    const float* xb = x + (size_t)b * Cin * HW;
    for (int c = 0; c < Cin; ++c) {
        float xv[9];
#pragma unroll
        for (int ty = 0; ty < 3; ++ty) {
            int yy = h - 1 + ty;
#pragma unroll
            for (int tx = 0; tx < 3; ++tx) {
                int xx = w - 1 + tx;
                bool ok = (yy >= 0) && (yy < Himg) && (xx >= 0) && (xx < Wimg);
                xv[ty * 3 + tx] = ok ? xb[c * HW + yy * Wimg + xx] : 0.0f;
            }
        }
#pragma unroll
        for (int j = 0; j < 18; ++j) {
#pragma unroll
            for (int t = 0; t < 9; ++t)
                acc[j] = fmaf(w_offset[(j * Cin + c) * 9 + t], xv[t], acc[j]);
        }
#pragma unroll
        for (int j = 0; j < 9; ++j) {
#pragma unroll
            for (int t = 0; t < 9; ++t)
                acc[18 + j] = fmaf(w_mask[(j * Cin + c) * 9 + t], xv[t], acc[18 + j]);
        }
    }

#pragma unroll
    for (int k = 0; k < 9; ++k) {
        int idx = (b * 9 + k) * HW + rem;
        dy_out[idx] = acc[2 * k];
        dx_out[idx] = acc[2 * k + 1];
        mk_out[idx] = 1.0f / (1.0f + expf(-acc[18 + k]));
    }
}

// ---------------------------------------------------------------------------
// Kernel 2: fused deformable sampling + einsum.
// Out(128 x Npix) = Wmat(128 x 576) * V(576 x Npix), V built on the fly.
// Block: 256 threads, 64 pixels (half a row). Per k: geometry once.
// K-dim chunked 16 channels at a time; V-tile + W-tile staged in LDS;
// each thread register-blocks 4 outputs x 8 pixels.
// ---------------------------------------------------------------------------
#define PPB 64
__global__ __launch_bounds__(256) void deform_gemm(
        const float* __restrict__ x, const float* __restrict__ wpk,
        const float* __restrict__ dy_ws, const float* __restrict__ dx_ws,
        const float* __restrict__ mk_ws, float* __restrict__ out) {
    __shared__ float v_tile[16][PPB];      // 4 KB
    __shared__ float w_tile[16][OUTC];     // 8 KB

    int t    = threadIdx.x;
    int bid  = blockIdx.x;
    int b    = bid >> 8;                   // 256 blocks per batch image
    int pix0 = (bid & 255) * PPB;
    int h    = pix0 >> 7;                  // fixed per block
    int w0   = pix0 & 127;                 // 0 or 64

    // sampling-role mapping
    int p  = t & 63;                       // pixel 0..63
    int cb = (t >> 6) * 4;                 // channel sub-base {0,4,8,12}
    // compute-role mapping
    int og = t >> 3;                       // output group 0..31 (4 outs each)
    int pg = (t & 7) * 8;                  // pixel group start (8 pixels)

    float acc[4][8];
#pragma unroll
    for (int i = 0; i < 4; ++i)
#pragma unroll
        for (int j = 0; j < 8; ++j) acc[i][j] = 0.0f;

    const float* xb = x + (size_t)b * Cin * HW;
    int w_pix = w0 + p;

    for (int k = 0; k < 9; ++k) {
        int sidx = (b * 9 + k) * HW + pix0 + p;
        float dy = dy_ws[sidx];
        float dx = dx_ws[sidx];
        float mk = mk_ws[sidx];

        float gy  = (float)h - 1.0f + (float)(k / 3) + dy;
        float gx  = (float)w_pix - 1.0f + (float)(k % 3) + dx;
        float y0f = floorf(gy), x0f = floorf(gx);
        int   y0  = (int)y0f,   x0i = (int)x0f;
        float wy  = gy - y0f,   wx  = gx - x0f;
        int   y1  = y0 + 1,     x1i = x0i + 1;

        bool vy0 = (y0  >= 0) && (y0  < Himg);
        bool vy1 = (y1  >= 0) && (y1  < Himg);
        bool vx0 = (x0i >= 0) && (x0i < Wimg);
        bool vx1 = (x1i >= 0) && (x1i < Wimg);

        float w00 = (vy0 && vx0) ? (1.0f - wy) * (1.0f - wx) * mk : 0.0f;
        float w01 = (vy0 && vx1) ? (1.0f - wy) * wx          * mk : 0.0f;
        float w10 = (vy1 && vx0) ? wy          * (1.0f - wx) * mk : 0.0f;
        float w11 = (vy1 && vx1) ? wy          * wx          * mk : 0.0f;

        int y0c = min(max(y0, 0), Himg - 1), y1c = min(max(y1, 0), Himg - 1);
        int x0c = min(max(x0i, 0), Wimg - 1), x1c = min(max(x1i, 0), Wimg - 1);
        int o00 = y0c * Wimg + x0c, o01 = y0c * Wimg + x1c;
        int o10 = y1c * Wimg + x0c, o11 = y1c * Wimg + x1c;

        for (int cc = 0; cc < 4; ++cc) {
            int c0 = cc * 16;
            __syncthreads();               // protect previous tile's readers
            // --- build V tile: 16 channels x 64 pixels ---
#pragma unroll
            for (int i = 0; i < 4; ++i) {
                const float* xp = xb + (size_t)(c0 + cb + i) * HW;
                float v = w00 * xp[o00] + w01 * xp[o01] +
                          w10 * xp[o10] + w11 * xp[o11];
                v_tile[cb + i][p] = v;
            }
            // --- load W tile: 16 channels x 128 outputs (coalesced) ---
            const float4* wsrc = (const float4*)(wpk + (size_t)(k * Cin + c0) * OUTC);
            float4* wdst = (float4*)(&w_tile[0][0]);
            wdst[t]       = wsrc[t];
            wdst[t + 256] = wsrc[t + 256];
            __syncthreads();
            // --- accumulate 4 outs x 8 pixels over 16 channels ---
#pragma unroll
            for (int c = 0; c < 16; ++c) {
                float4 wv = *(const float4*)(&w_tile[c][og * 4]);
                float4 va = *(const float4*)(&v_tile[c][pg]);
                float4 vb = *(const float4*)(&v_tile[c][pg + 4]);
                float wv_[4] = {wv.x, wv.y, wv.z, wv.w};
                float vv_[8] = {va.x, va.y, va.z, va.w, vb.x, vb.y, vb.z, vb.w};
#pragma unroll
                for (int i = 0; i < 4; ++i)
#pragma unroll
                    for (int j = 0; j < 8; ++j)
                        acc[i][j] = fmaf(wv_[i], vv_[j], acc[i][j]);
            }
        }
    }

    // epilogue: coalesced float4 stores
#pragma unroll
    for (int i = 0; i < 4; ++i) {
        int o = og * 4 + i;
        float4 s0 = make_float4(acc[i][0], acc[i][1], acc[i][2], acc[i][3]);
        float4 s1 = make_float4(acc[i][4], acc[i][5], acc[i][6], acc[i][7]);
        float4* dst = (float4*)(out + (size_t)(b * OUTC + o) * HW + pix0 + pg);
        dst[0] = s0;
        dst[1] = s1;
    }
}

// ---------------------------------------------------------------------------
extern "C" void kernel_launch(void* const* d_in, const int* in_sizes, int n_in,
                              void* d_out, int out_size, void* d_ws, size_t ws_size,
                              hipStream_t stream) {
    const float* x        = (const float*)d_in[0];
    const float* w_offset = (const float*)d_in[1];
    const float* b_offset = (const float*)d_in[2];
    const float* w_mask   = (const float*)d_in[3];
    const float* b_mask   = (const float*)d_in[4];
    const float* w_conv   = (const float*)d_in[5];
    float* out = (float*)d_out;

    const size_t PLANE = (size_t)Bsz * Kk * HW;          // 1,179,648 floats
    float* ws    = (float*)d_ws;
    float* dy_ws = ws;
    float* dx_ws = ws + PLANE;
    float* mk_ws = ws + 2 * PLANE;
    float* wpk   = ws + 3 * PLANE;                       // 73,728 floats

    repack_w<<<288, 256, 0, stream>>>(w_conv, wpk);
    offs_mask<<<512, 256, 0, stream>>>(x, w_offset, b_offset, w_mask, b_mask,
                                       dy_ws, dx_ws, mk_ws);
    deform_gemm<<<2048, 256, 0, stream>>>(x, wpk, dy_ws, dx_ws, mk_ws, out);
}